// Round 9
// baseline (395.571 us; speedup 1.0000x reference)
//
#include <hip/hip_runtime.h>
#include <hip/hip_bf16.h>

typedef __attribute__((ext_vector_type(8))) short short8;
typedef __attribute__((ext_vector_type(4))) float f32x4;

#define N0 65536
#define N1 16384
#define N2 4096
#define N3 1024

// ---------------------------------------------------------------------------
// Weight prep (all 4 tensors in one launch; dst buffers contiguous):
// Wt[k][d][c] = bf16(W[k][c][d])
// ---------------------------------------------------------------------------
__global__ void prep_w4(const float* __restrict__ A, const float* __restrict__ B,
                        const float* __restrict__ C, const float* __restrict__ D,
                        __hip_bfloat16* __restrict__ dst, int total)
{
    int i = blockIdx.x * 256 + threadIdx.x;
    if (i >= total) return;
    int k = i >> 12, r = i & 4095, d = r >> 6, c = r & 63;
    const float* src; int kl;
    if (k < 27)      { src = A; kl = k; }
    else if (k < 54) { src = B; kl = k - 27; }
    else if (k < 81) { src = C; kl = k - 54; }
    else             { src = D; kl = k - 81; }
    dst[i] = __float2bfloat16(src[(kl << 12) + (c << 6) + d]);
}

// ---------------------------------------------------------------------------
// MFMA sparse conv (r3-proven 64-row geometry): 256 threads = 4 waves; each
// wave 16 rows x 64 cols (4 col-tiles of 16x16x32). Per block-tap: A 64x64 +
// B 64x64 staged via global_load_lds (4 loads/thread); 40 ds_read_b128 feed
// 32 MFMAs. LDS 39KB -> 4 blocks/CU.
// K-loop: counted pipeline (r8-proven-correct): stage(k+1) [4 loads] ->
// vmcnt(4) -> raw s_barrier -> compute(k) -> raw s_barrier.
// LDS XOR-swizzle: 16B-chunk q of row r holds global chunk q^(r&7) (rule #21).
// mode 0: store bf16 raw; mode 2: bf16 bias+relu;
// mode 1: store f32 partial to chunk buffer blockIdx.y (NO atomics/memset) —
//         chunk c's buffer is outp + c*Nout*64 floats; reduced downstream.
// ---------------------------------------------------------------------------
__global__ __launch_bounds__(256) void spconv_mfma(
    const __hip_bfloat16* __restrict__ feat, const int* __restrict__ nmap,
    const __hip_bfloat16* __restrict__ Wt, void* __restrict__ outp,
    const float* __restrict__ bias, int Nout, int K, int mode)
{
    __shared__ short Abuf[2][64 * 64];   // 16 KB
    __shared__ short Bbuf[2][64 * 64];   // 16 KB
    __shared__ int jl[27 * 64];          // 6.9 KB

    const int t = threadIdx.x;
    const int w = t >> 6, l = t & 63;
    const int lr = l & 15, lh = l >> 4;
    const int row0 = blockIdx.x * 64;
    const int per = (K + gridDim.y - 1) / gridDim.y;
    const int kb0 = blockIdx.y * per;
    const int nk = min(K, kb0 + per) - kb0;

    for (int i = t; i < nk * 64; i += 256) {
        int k = i >> 6, r = i & 63;
        jl[i] = nmap[(size_t)(row0 + r) * K + (kb0 + k)];
    }
    __syncthreads();   // jl visible (one-time drain)

    // staging: wave w, iter i covers rows w*16 + i*8 + (l>>3), chunk l&7;
    // LDS dest = wave-uniform base + lane*16B (linear); global source chunk
    // is inverse-swizzled qq = (l&7)^(l>>3)  (row&7 == l>>3 here).
    const int rr0 = (w << 4) + (l >> 3);
    const int qq = (l & 7) ^ (l >> 3);

    auto stage = [&](int buf, int k) {
        const __hip_bfloat16* Wk = Wt + (size_t)(kb0 + k) * 4096;
#pragma unroll
        for (int i = 0; i < 2; ++i) {
            int rr = rr0 + (i << 3);
            int j = jl[(k << 6) + rr];
            __builtin_amdgcn_global_load_lds(
                (const __attribute__((address_space(1))) void*)(feat + ((size_t)j << 6) + (qq << 3)),
                (__attribute__((address_space(3))) void*)&Abuf[buf][(w << 10) + (i << 9)],
                16, 0, 0);
            __builtin_amdgcn_global_load_lds(
                (const __attribute__((address_space(1))) void*)(Wk + (rr << 6) + (qq << 3)),
                (__attribute__((address_space(3))) void*)&Bbuf[buf][(w << 10) + (i << 9)],
                16, 0, 0);
        }
    };

    f32x4 acc[4] = {};
    const int arow = (w << 4) + lr;

#define COMPUTE(cur_)                                                            \
    {                                                                            \
        const short* Ab = Abuf[cur_];                                            \
        const short* Bb = Bbuf[cur_];                                            \
        _Pragma("unroll")                                                        \
        for (int kk = 0; kk < 2; ++kk) {                                         \
            int q = (kk << 2) + lh;                                              \
            short8 a = *(const short8*)&Ab[(arow << 6) + ((q ^ (arow & 7)) << 3)];\
            _Pragma("unroll")                                                    \
            for (int ct = 0; ct < 4; ++ct) {                                     \
                int dr = (ct << 4) + lr;                                         \
                short8 b = *(const short8*)&Bb[(dr << 6) + ((q ^ (dr & 7)) << 3)];\
                acc[ct] = __builtin_amdgcn_mfma_f32_16x16x32_bf16(a, b, acc[ct], 0, 0, 0); \
            }                                                                    \
        }                                                                        \
    }

    stage(0, 0);

    int cur = 0;
    for (int k = 0; k < nk; ++k) {
        if (k + 1 < nk) {
            stage(cur ^ 1, k + 1);
            asm volatile("s_waitcnt vmcnt(4)" ::: "memory");   // tile k landed; k+1 in flight
        } else {
            asm volatile("s_waitcnt vmcnt(0)" ::: "memory");
        }
        asm volatile("s_barrier" ::: "memory");                // B1: tile k visible
        COMPUTE(cur);
        asm volatile("s_barrier" ::: "memory");                // B2: reads done before overwrite
        cur ^= 1;
    }
#undef COMPUTE

    // epilogue: C/D layout col = lane&15 (+ct*16), row = (lane>>4)*4 + reg
    if (mode == 1) {
        float* o32 = (float*)outp + (size_t)blockIdx.y * ((size_t)Nout << 6);
#pragma unroll
        for (int ct = 0; ct < 4; ++ct) {
            int col = (ct << 4) + lr;
#pragma unroll
            for (int rr = 0; rr < 4; ++rr) {
                int row = row0 + (w << 4) + (lh << 2) + rr;
                o32[((size_t)row << 6) + col] = acc[ct][rr];
            }
        }
    } else {
        __hip_bfloat16* ob = (__hip_bfloat16*)outp;
#pragma unroll
        for (int ct = 0; ct < 4; ++ct) {
            int col = (ct << 4) + lr;
            float bv = (mode == 2) ? bias[col] : 0.f;
#pragma unroll
            for (int rr = 0; rr < 4; ++rr) {
                int row = row0 + (w << 4) + (lh << 2) + rr;
                float v = acc[ct][rr];
                if (mode == 2) v = fmaxf(v + bv, 0.f);
                ob[((size_t)row << 6) + col] = __float2bfloat16(v);
            }
        }
    }
}

// ---------------------------------------------------------------------------
// reduce_relu_bf: out_bf16 = relu(sum_ch chunk + bias[c])  over [N][64]
// chunk c at in + c*nv float4s (nv = N*16).
// ---------------------------------------------------------------------------
__global__ void reduce_relu_bf(const float* __restrict__ in, const float* __restrict__ bias,
                               __hip_bfloat16* __restrict__ outb, int nv, int ch)
{
    int i = blockIdx.x * blockDim.x + threadIdx.x;
    if (i >= nv) return;
    const float4* in4 = (const float4*)in;
    float4 s = in4[i];
    for (int c = 1; c < ch; ++c) {
        float4 v = in4[(size_t)c * nv + i];
        s.x += v.x; s.y += v.y; s.z += v.z; s.w += v.w;
    }
    int cb = (i << 2) & 63;
    ushort4 o;
    o.x = __builtin_bit_cast(unsigned short, __float2bfloat16(fmaxf(s.x + bias[cb + 0], 0.f)));
    o.y = __builtin_bit_cast(unsigned short, __float2bfloat16(fmaxf(s.y + bias[cb + 1], 0.f)));
    o.z = __builtin_bit_cast(unsigned short, __float2bfloat16(fmaxf(s.z + bias[cb + 2], 0.f)));
    o.w = __builtin_bit_cast(unsigned short, __float2bfloat16(fmaxf(s.w + bias[cb + 3], 0.f)));
    ((ushort4*)outb)[i] = o;
}

// ---------------------------------------------------------------------------
// epi_full: thread-per-row, LDS-staged weights, fully unrolled registers.
//   t = act(src); hx = t@Wout+bout -> hx_out; g = sigmoid(hx@Wg+bg);
//   gout = bf16(g*t)
// smode 0: src bf16 +bias+relu; 2: src f32 raw;
// smode 3: src = ch f32 chunk buffers (stride N*64 floats), summed, +bias+relu.
// ---------------------------------------------------------------------------
__global__ __launch_bounds__(256) void epi_full(
    const void* __restrict__ srcp, int smode, int ch, const float* __restrict__ bconv,
    const float* __restrict__ Wout, const float* __restrict__ bout,
    const float* __restrict__ Wg, const float* __restrict__ bg,
    float* __restrict__ hx_out, __hip_bfloat16* __restrict__ gout, int N)
{
    __shared__ float Woutl[64 * 32];
    __shared__ float Wgl[32 * 64];
    __shared__ float boutl[32];
    __shared__ float bgl[64];
    __shared__ float bcl[64];

    const int t = threadIdx.x;
    for (int i = t; i < 2048; i += 256) { Woutl[i] = Wout[i]; Wgl[i] = Wg[i]; }
    if (t < 32) boutl[t] = bout[t];
    if (t >= 64 && t < 128) bgl[t - 64] = bg[t - 64];
    if (t >= 128 && t < 192) bcl[t - 128] = bconv ? bconv[t - 128] : 0.f;
    __syncthreads();

    const int row = blockIdx.x * 256 + t;

    float tv[64];
    if (smode == 0) {
        const ushort4* sb = (const ushort4*)((const __hip_bfloat16*)srcp + ((size_t)row << 6));
#pragma unroll
        for (int i = 0; i < 16; ++i) {
            ushort4 v = sb[i];
            tv[i * 4 + 0] = __bfloat162float(__builtin_bit_cast(__hip_bfloat16, v.x));
            tv[i * 4 + 1] = __bfloat162float(__builtin_bit_cast(__hip_bfloat16, v.y));
            tv[i * 4 + 2] = __bfloat162float(__builtin_bit_cast(__hip_bfloat16, v.z));
            tv[i * 4 + 3] = __bfloat162float(__builtin_bit_cast(__hip_bfloat16, v.w));
        }
    } else if (smode == 2) {
        const float4* sf = (const float4*)((const float*)srcp + ((size_t)row << 6));
#pragma unroll
        for (int i = 0; i < 16; ++i) {
            float4 v = sf[i];
            tv[i * 4 + 0] = v.x; tv[i * 4 + 1] = v.y;
            tv[i * 4 + 2] = v.z; tv[i * 4 + 3] = v.w;
        }
    } else {  // smode 3: sum ch chunk buffers
        const float4* sf = (const float4*)srcp + (size_t)row * 16;
        const size_t cstride = (size_t)N * 16;
#pragma unroll
        for (int i = 0; i < 16; ++i) {
            float4 v = sf[i];
            for (int c = 1; c < ch; ++c) {
                float4 u = sf[(size_t)c * cstride + i];
                v.x += u.x; v.y += u.y; v.z += u.z; v.w += u.w;
            }
            tv[i * 4 + 0] = v.x; tv[i * 4 + 1] = v.y;
            tv[i * 4 + 2] = v.z; tv[i * 4 + 3] = v.w;
        }
    }
    if (smode != 2) {
#pragma unroll
        for (int c = 0; c < 64; ++c) tv[c] = fmaxf(tv[c] + bcl[c], 0.f);
    }

    float hx[32];
#pragma unroll
    for (int d = 0; d < 32; ++d) hx[d] = boutl[d];
#pragma unroll
    for (int c = 0; c < 64; ++c) {
        float tc = tv[c];
        const f32x4* wr = (const f32x4*)&Woutl[c << 5];
#pragma unroll
        for (int d4 = 0; d4 < 8; ++d4) {
            f32x4 wv = wr[d4];
            hx[d4 * 4 + 0] = fmaf(tc, wv[0], hx[d4 * 4 + 0]);
            hx[d4 * 4 + 1] = fmaf(tc, wv[1], hx[d4 * 4 + 1]);
            hx[d4 * 4 + 2] = fmaf(tc, wv[2], hx[d4 * 4 + 2]);
            hx[d4 * 4 + 3] = fmaf(tc, wv[3], hx[d4 * 4 + 3]);
        }
    }
    {
        float* ho = hx_out + ((size_t)row << 5);
#pragma unroll
        for (int i = 0; i < 8; ++i) {
            float4 v = {hx[i * 4 + 0], hx[i * 4 + 1], hx[i * 4 + 2], hx[i * 4 + 3]};
            ((float4*)ho)[i] = v;
        }
    }

    __hip_bfloat16* go = gout + ((size_t)row << 6);
#pragma unroll
    for (int jc = 0; jc < 2; ++jc) {
        float acc[32];
#pragma unroll
        for (int jj = 0; jj < 32; ++jj) acc[jj] = bgl[jc * 32 + jj];
#pragma unroll
        for (int d = 0; d < 32; ++d) {
            float hd = hx[d];
            const f32x4* wr = (const f32x4*)&Wgl[(d << 6) + jc * 32];
#pragma unroll
            for (int j4 = 0; j4 < 8; ++j4) {
                f32x4 wv = wr[j4];
                acc[j4 * 4 + 0] = fmaf(hd, wv[0], acc[j4 * 4 + 0]);
                acc[j4 * 4 + 1] = fmaf(hd, wv[1], acc[j4 * 4 + 1]);
                acc[j4 * 4 + 2] = fmaf(hd, wv[2], acc[j4 * 4 + 2]);
                acc[j4 * 4 + 3] = fmaf(hd, wv[3], acc[j4 * 4 + 3]);
            }
        }
        unsigned short ob[32];
#pragma unroll
        for (int jj = 0; jj < 32; ++jj) {
            float gg = 1.f / (1.f + __expf(-acc[jj]));
            ob[jj] = __builtin_bit_cast(unsigned short,
                         __float2bfloat16(gg * tv[jc * 32 + jj]));
        }
#pragma unroll
        for (int i = 0; i < 8; ++i) {
            ushort4 v = {ob[i * 4 + 0], ob[i * 4 + 1], ob[i * 4 + 2], ob[i * 4 + 3]};
            ((ushort4*)go)[jc * 8 + i] = v;
        }
    }
}

// ---------------------------------------------------------------------------
extern "C" void kernel_launch(void* const* d_in, const int* in_sizes, int n_in,
                              void* d_out, int out_size, void* d_ws, size_t ws_size,
                              hipStream_t stream)
{
    const float* x    = (const float*)d_in[0];
    const float* Wg0  = (const float*)d_in[1];
    const float* bg0  = (const float*)d_in[2];
    const float* Wg1  = (const float*)d_in[3];
    const float* bg1  = (const float*)d_in[4];
    const float* Wout = (const float*)d_in[5];
    const float* bout = (const float*)d_in[6];
    const float* WA   = (const float*)d_in[7];
    const float* bA   = (const float*)d_in[8];
    const float* WB   = (const float*)d_in[9];
    const float* bB   = (const float*)d_in[10];
    const float* WD   = (const float*)d_in[11];
    const float* bD   = (const float*)d_in[12];
    const float* WC   = (const float*)d_in[13];
    const float* bC   = (const float*)d_in[14];
    const int* nmap[4] = {(const int*)d_in[15], (const int*)d_in[16],
                          (const int*)d_in[17], (const int*)d_in[18]};
    const int* ndm[3]  = {(const int*)d_in[19], (const int*)d_in[20],
                          (const int*)d_in[21]};

    float* out = (float*)d_out;
    __hip_bfloat16* featbf0 = (__hip_bfloat16*)d_ws;
    __hip_bfloat16* featbf1 = featbf0 + (size_t)N0 * 64;
    __hip_bfloat16* convbf  = featbf1 + (size_t)N0 * 64;
    float* conv32 = (float*)(convbf + (size_t)N0 * 64);   // up to 7 chunks of N2*64 f32 (7MB)
    __hip_bfloat16* WAt = (__hip_bfloat16*)(conv32 + (size_t)N2 * 64 * 8);
    __hip_bfloat16* WBt = WAt + 27 * 4096;
    __hip_bfloat16* WCt = WBt + 27 * 4096;
    __hip_bfloat16* WDt = WCt + 27 * 4096;

    const int Ns[4] = {N0, N1, N2, N3};
    size_t off[7];
    off[0] = 0;
    off[1] = off[0] + (size_t)N0 * 32;
    off[2] = off[1] + (size_t)N0 * 32;
    off[3] = off[2] + (size_t)N1 * 32;
    off[4] = off[3] + (size_t)N1 * 32;
    off[5] = off[4] + (size_t)N2 * 32;
    off[6] = off[5] + (size_t)N2 * 32;

    hipLaunchKernelGGL(prep_w4, dim3((89 * 4096 + 255) / 256), dim3(256), 0, stream,
                       WA, WB, WC, WD, WAt, 89 * 4096);

    // big scales run direct; small scales tap-split into ch partial buffers
    auto chunks = [&](int Nout, int K) -> int {
        if (Nout >= 16384) return 1;
        if (Nout == 4096) return (K == 27) ? 7 : 4;
        return (K == 27) ? 14 : 8;   // N3 (14*1024*64*4B = 3.7MB < 8MB region)
    };
    // returns ch if result is f32 chunk partials in conv32, else 0 (bf16 in dst)
    auto conv = [&](const __hip_bfloat16* fin, const int* nm,
                    const __hip_bfloat16* Wt, int Nout, int K,
                    const float* bias2, void* dst, int mode) -> int {
        int ch = chunks(Nout, K);
        if (ch > 1) {
            hipLaunchKernelGGL(spconv_mfma, dim3(Nout / 64, ch), dim3(256), 0, stream,
                               fin, nm, Wt, (void*)conv32, (const float*)nullptr,
                               Nout, K, 1);
            return ch;
        }
        hipLaunchKernelGGL(spconv_mfma, dim3(Nout / 64, 1), dim3(256), 0, stream,
                           fin, nm, Wt, dst, bias2, Nout, K, mode);
        return 0;
    };

    // init: hx0 -> out0 ; featbf0 = bf16(sigmoid(hx0@Wg0+bg0) * x)
    hipLaunchKernelGGL(epi_full, dim3(N0 / 256), dim3(256), 0, stream,
                       (const void*)x, 2, 1, (const float*)nullptr, Wout, bout, Wg0, bg0,
                       out + off[0], featbf0, N0);

    for (int s = 0; s < 3; ++s) {
        int N = Ns[s], Nn = Ns[s + 1];

        // conv A (bias+relu) -> featbf1
        int mA = conv(featbf0, nmap[s], WAt, N, 27, bA, featbf1, 2);
        if (mA)
            hipLaunchKernelGGL(reduce_relu_bf, dim3((N * 16 + 255) / 256), dim3(256), 0, stream,
                               conv32, bA, featbf1, N * 16, mA);
        // conv B (raw) -> convbf or conv32 chunks ; epilogue fuses reduce+bias+relu+hx+gate
        int mB = conv(featbf1, nmap[s], WBt, N, 27, nullptr, convbf, 0);
        hipLaunchKernelGGL(epi_full, dim3(N / 256), dim3(256), 0, stream,
                           mB ? (const void*)conv32 : (const void*)convbf, mB ? 3 : 0, mB, bB,
                           Wout, bout, Wg1, bg1, out + off[s * 2 + 1], featbf0, N);

        // conv D (downsample, bias+relu) -> featbf1
        int mD = conv(featbf0, ndm[s], WDt, Nn, 8, bD, featbf1, 2);
        if (mD)
            hipLaunchKernelGGL(reduce_relu_bf, dim3((Nn * 16 + 255) / 256), dim3(256), 0, stream,
                               conv32, bD, featbf1, Nn * 16, mD);
        // conv C (raw) -> convbf or conv32 chunks ; epilogue
        int mC = conv(featbf1, nmap[s + 1], WCt, Nn, 27, nullptr, convbf, 0);
        hipLaunchKernelGGL(epi_full, dim3(Nn / 256), dim3(256), 0, stream,
                           mC ? (const void*)conv32 : (const void*)convbf, mC ? 3 : 0, mC, bC,
                           Wout, bout, Wg0, bg0, out + off[s * 2 + 2], featbf0, Nn);
    }
}

// Round 10
// 274.818 us; speedup vs baseline: 1.4394x; 1.4394x over previous
//
#include <hip/hip_runtime.h>
#include <hip/hip_bf16.h>

typedef __attribute__((ext_vector_type(8))) short short8;
typedef __attribute__((ext_vector_type(4))) float f32x4;

#define N0 65536
#define N1 16384
#define N2 4096
#define N3 1024

// ---------------------------------------------------------------------------
// Weight prep (all 4 tensors in one launch; dst buffers contiguous):
// Wt[k][d][c] = bf16(W[k][c][d])
// ---------------------------------------------------------------------------
__global__ void prep_w4(const float* __restrict__ A, const float* __restrict__ B,
                        const float* __restrict__ C, const float* __restrict__ D,
                        __hip_bfloat16* __restrict__ dst, int total)
{
    int i = blockIdx.x * 256 + threadIdx.x;
    if (i >= total) return;
    int k = i >> 12, r = i & 4095, d = r >> 6, c = r & 63;
    const float* src; int kl;
    if (k < 27)      { src = A; kl = k; }
    else if (k < 54) { src = B; kl = k - 27; }
    else if (k < 81) { src = C; kl = k - 54; }
    else             { src = D; kl = k - 81; }
    dst[i] = __float2bfloat16(src[(kl << 12) + (c << 6) + d]);
}

// ---------------------------------------------------------------------------
// MFMA sparse conv (r3/r9-proven 64-row geometry, counted vmcnt pipeline).
// mode 0: store bf16 raw; mode 2: bf16 bias+relu;
// mode 1: store f32 partial to chunk buffer blockIdx.y (no atomics/memset).
// ---------------------------------------------------------------------------
__global__ __launch_bounds__(256) void spconv_mfma(
    const __hip_bfloat16* __restrict__ feat, const int* __restrict__ nmap,
    const __hip_bfloat16* __restrict__ Wt, void* __restrict__ outp,
    const float* __restrict__ bias, int Nout, int K, int mode)
{
    __shared__ short Abuf[2][64 * 64];   // 16 KB
    __shared__ short Bbuf[2][64 * 64];   // 16 KB
    __shared__ int jl[27 * 64];          // 6.9 KB

    const int t = threadIdx.x;
    const int w = t >> 6, l = t & 63;
    const int lr = l & 15, lh = l >> 4;
    const int row0 = blockIdx.x * 64;
    const int per = (K + gridDim.y - 1) / gridDim.y;
    const int kb0 = blockIdx.y * per;
    const int nk = min(K, kb0 + per) - kb0;

    for (int i = t; i < nk * 64; i += 256) {
        int k = i >> 6, r = i & 63;
        jl[i] = nmap[(size_t)(row0 + r) * K + (kb0 + k)];
    }
    __syncthreads();   // jl visible (one-time drain)

    const int rr0 = (w << 4) + (l >> 3);
    const int qq = (l & 7) ^ (l >> 3);

    auto stage = [&](int buf, int k) {
        const __hip_bfloat16* Wk = Wt + (size_t)(kb0 + k) * 4096;
#pragma unroll
        for (int i = 0; i < 2; ++i) {
            int rr = rr0 + (i << 3);
            int j = jl[(k << 6) + rr];
            __builtin_amdgcn_global_load_lds(
                (const __attribute__((address_space(1))) void*)(feat + ((size_t)j << 6) + (qq << 3)),
                (__attribute__((address_space(3))) void*)&Abuf[buf][(w << 10) + (i << 9)],
                16, 0, 0);
            __builtin_amdgcn_global_load_lds(
                (const __attribute__((address_space(1))) void*)(Wk + (rr << 6) + (qq << 3)),
                (__attribute__((address_space(3))) void*)&Bbuf[buf][(w << 10) + (i << 9)],
                16, 0, 0);
        }
    };

    f32x4 acc[4] = {};
    const int arow = (w << 4) + lr;

#define COMPUTE(cur_)                                                            \
    {                                                                            \
        const short* Ab = Abuf[cur_];                                            \
        const short* Bb = Bbuf[cur_];                                            \
        _Pragma("unroll")                                                        \
        for (int kk = 0; kk < 2; ++kk) {                                         \
            int q = (kk << 2) + lh;                                              \
            short8 a = *(const short8*)&Ab[(arow << 6) + ((q ^ (arow & 7)) << 3)];\
            _Pragma("unroll")                                                    \
            for (int ct = 0; ct < 4; ++ct) {                                     \
                int dr = (ct << 4) + lr;                                         \
                short8 b = *(const short8*)&Bb[(dr << 6) + ((q ^ (dr & 7)) << 3)];\
                acc[ct] = __builtin_amdgcn_mfma_f32_16x16x32_bf16(a, b, acc[ct], 0, 0, 0); \
            }                                                                    \
        }                                                                        \
    }

    stage(0, 0);

    int cur = 0;
    for (int k = 0; k < nk; ++k) {
        if (k + 1 < nk) {
            stage(cur ^ 1, k + 1);
            asm volatile("s_waitcnt vmcnt(4)" ::: "memory");
        } else {
            asm volatile("s_waitcnt vmcnt(0)" ::: "memory");
        }
        asm volatile("s_barrier" ::: "memory");
        COMPUTE(cur);
        asm volatile("s_barrier" ::: "memory");
        cur ^= 1;
    }
#undef COMPUTE

    if (mode == 1) {
        float* o32 = (float*)outp + (size_t)blockIdx.y * ((size_t)Nout << 6);
#pragma unroll
        for (int ct = 0; ct < 4; ++ct) {
            int col = (ct << 4) + lr;
#pragma unroll
            for (int rr = 0; rr < 4; ++rr) {
                int row = row0 + (w << 4) + (lh << 2) + rr;
                o32[((size_t)row << 6) + col] = acc[ct][rr];
            }
        }
    } else {
        __hip_bfloat16* ob = (__hip_bfloat16*)outp;
#pragma unroll
        for (int ct = 0; ct < 4; ++ct) {
            int col = (ct << 4) + lr;
            float bv = (mode == 2) ? bias[col] : 0.f;
#pragma unroll
            for (int rr = 0; rr < 4; ++rr) {
                int row = row0 + (w << 4) + (lh << 2) + rr;
                float v = acc[ct][rr];
                if (mode == 2) v = fmaxf(v + bv, 0.f);
                ob[((size_t)row << 6) + col] = __float2bfloat16(v);
            }
        }
    }
}

// ---------------------------------------------------------------------------
// reduce_relu_bf: out_bf16 = relu(sum_ch chunk + bias[c])  over [N][64]
// ---------------------------------------------------------------------------
__global__ void reduce_relu_bf(const float* __restrict__ in, const float* __restrict__ bias,
                               __hip_bfloat16* __restrict__ outb, int nv, int ch)
{
    int i = blockIdx.x * blockDim.x + threadIdx.x;
    if (i >= nv) return;
    const float4* in4 = (const float4*)in;
    float4 s = in4[i];
    for (int c = 1; c < ch; ++c) {
        float4 v = in4[(size_t)c * nv + i];
        s.x += v.x; s.y += v.y; s.z += v.z; s.w += v.w;
    }
    int cb = (i << 2) & 63;
    ushort4 o;
    o.x = __builtin_bit_cast(unsigned short, __float2bfloat16(fmaxf(s.x + bias[cb + 0], 0.f)));
    o.y = __builtin_bit_cast(unsigned short, __float2bfloat16(fmaxf(s.y + bias[cb + 1], 0.f)));
    o.z = __builtin_bit_cast(unsigned short, __float2bfloat16(fmaxf(s.z + bias[cb + 2], 0.f)));
    o.w = __builtin_bit_cast(unsigned short, __float2bfloat16(fmaxf(s.w + bias[cb + 3], 0.f)));
    ((ushort4*)outb)[i] = o;
}

// ---------------------------------------------------------------------------
// epi_full — 8-LANES-PER-ROW rewrite (fixes the 57us serial/spill dispatch):
// 256 threads = 32 rows/block; lane group g = t&7 owns channels g*8..g*8+7.
// Per lane: tv[8] (+chunk sum) -> partial ph[32] over its 8 channels ->
// 3-round __shfl_xor butterfly (all 8 lanes end with full hx[32]) -> +bout ->
// hx_out (lane g stores hx[4g..4g+3] via compile-time-unrolled select) ->
// gate: 8 outputs per lane -> sigmoid -> gout bf16.
// ~70 VGPR, no runtime-indexed register arrays, no scratch.
// Woutl is stored chunk-XOR-swizzled: float4-chunk q of row r lives at
// q^(r>>3) — the 8 lanes of a group read rows differing by 8, so the natural
// layout would be an 8-way bank conflict; XOR by (r>>3)=g spreads them.
// smode 0: src bf16 +bias+relu; 2: src f32 raw; 3: ch f32 chunks summed +bias+relu.
// ---------------------------------------------------------------------------
__global__ __launch_bounds__(256) void epi_full(
    const void* __restrict__ srcp, int smode, int ch, const float* __restrict__ bconv,
    const float* __restrict__ Wout, const float* __restrict__ bout,
    const float* __restrict__ Wg, const float* __restrict__ bg,
    float* __restrict__ hx_out, __hip_bfloat16* __restrict__ gout, int N)
{
    __shared__ float Woutl[64 * 32];   // [row r][chunk q^(r>>3)][4]
    __shared__ float Wgl[32 * 64];     // linear [d][j]
    __shared__ float boutl[32];
    __shared__ float bgl[64];
    __shared__ float bcl[64];

    const int t = threadIdx.x;
    for (int i = t; i < 2048; i += 256) {
        int r = i >> 5, col = i & 31;
        int q = col >> 2, e = col & 3;
        Woutl[(r << 5) + ((q ^ (r >> 3)) << 2) + e] = Wout[i];
        Wgl[i] = Wg[i];
    }
    if (t < 32) boutl[t] = bout[t];
    if (t >= 64 && t < 128) bgl[t - 64] = bg[t - 64];
    if (t >= 128 && t < 192) bcl[t - 128] = bconv ? bconv[t - 128] : 0.f;
    __syncthreads();

    const int g = t & 7;
    const int row = blockIdx.x * 32 + (t >> 3);
    const int c0 = g << 3;

    // ---- tv[8]: my 8 channels of act(src) ----
    float tv[8];
    if (smode == 0) {
        const ushort4* sb = (const ushort4*)((const __hip_bfloat16*)srcp + ((size_t)row << 6) + c0);
        ushort4 v0 = sb[0], v1 = sb[1];
        tv[0] = __bfloat162float(__builtin_bit_cast(__hip_bfloat16, v0.x));
        tv[1] = __bfloat162float(__builtin_bit_cast(__hip_bfloat16, v0.y));
        tv[2] = __bfloat162float(__builtin_bit_cast(__hip_bfloat16, v0.z));
        tv[3] = __bfloat162float(__builtin_bit_cast(__hip_bfloat16, v0.w));
        tv[4] = __bfloat162float(__builtin_bit_cast(__hip_bfloat16, v1.x));
        tv[5] = __bfloat162float(__builtin_bit_cast(__hip_bfloat16, v1.y));
        tv[6] = __bfloat162float(__builtin_bit_cast(__hip_bfloat16, v1.z));
        tv[7] = __bfloat162float(__builtin_bit_cast(__hip_bfloat16, v1.w));
    } else {
        const float4* sf = (const float4*)((const float*)srcp + ((size_t)row << 6) + c0);
        float4 a = sf[0], b = sf[1];
        if (smode == 3) {
            const size_t cs = (size_t)N * 16;   // chunk stride in float4s
            for (int c = 1; c < ch; ++c) {
                float4 u = sf[c * cs], v = sf[c * cs + 1];
                a.x += u.x; a.y += u.y; a.z += u.z; a.w += u.w;
                b.x += v.x; b.y += v.y; b.z += v.z; b.w += v.w;
            }
        }
        tv[0] = a.x; tv[1] = a.y; tv[2] = a.z; tv[3] = a.w;
        tv[4] = b.x; tv[5] = b.y; tv[6] = b.z; tv[7] = b.w;
    }
    if (smode != 2) {
#pragma unroll
        for (int i = 0; i < 8; ++i) tv[i] = fmaxf(tv[i] + bcl[c0 + i], 0.f);
    }

    // ---- partial hx over my 8 channels ----
    float ph[32];
#pragma unroll
    for (int d = 0; d < 32; ++d) ph[d] = 0.f;
#pragma unroll
    for (int i = 0; i < 8; ++i) {
        float tc = tv[i];
        const float* wr = &Woutl[(c0 + i) << 5];   // chunks XOR g
#pragma unroll
        for (int q = 0; q < 8; ++q) {
            f32x4 wv = *(const f32x4*)&wr[(q ^ g) << 2];   // holds cols q*4..q*4+3
            ph[q * 4 + 0] = fmaf(tc, wv[0], ph[q * 4 + 0]);
            ph[q * 4 + 1] = fmaf(tc, wv[1], ph[q * 4 + 1]);
            ph[q * 4 + 2] = fmaf(tc, wv[2], ph[q * 4 + 2]);
            ph[q * 4 + 3] = fmaf(tc, wv[3], ph[q * 4 + 3]);
        }
    }
    // ---- butterfly across the 8-lane group: all lanes get full sums ----
#pragma unroll
    for (int m = 1; m < 8; m <<= 1) {
#pragma unroll
        for (int d = 0; d < 32; ++d) ph[d] += __shfl_xor(ph[d], m);
    }
#pragma unroll
    for (int d = 0; d < 32; ++d) ph[d] += boutl[d];

    // ---- hx_out: lane g writes hx[4g..4g+3] (compile-time select) ----
    {
        float* ho = hx_out + ((size_t)row << 5);
#pragma unroll
        for (int G = 0; G < 8; ++G)
            if (g == G) {
                float4 v = {ph[G * 4 + 0], ph[G * 4 + 1], ph[G * 4 + 2], ph[G * 4 + 3]};
                ((float4*)ho)[G] = v;
            }
    }

    // ---- gate: my 8 outputs; gout = bf16(sigmoid(ga) * tv) ----
    float ga[8];
#pragma unroll
    for (int j = 0; j < 8; ++j) ga[j] = bgl[c0 + j];
#pragma unroll
    for (int d = 0; d < 32; ++d) {
        float hd = ph[d];
        const float* wr = &Wgl[(d << 6) + c0];
        f32x4 w0 = *(const f32x4*)&wr[0];
        f32x4 w1 = *(const f32x4*)&wr[4];
        ga[0] = fmaf(hd, w0[0], ga[0]); ga[1] = fmaf(hd, w0[1], ga[1]);
        ga[2] = fmaf(hd, w0[2], ga[2]); ga[3] = fmaf(hd, w0[3], ga[3]);
        ga[4] = fmaf(hd, w1[0], ga[4]); ga[5] = fmaf(hd, w1[1], ga[5]);
        ga[6] = fmaf(hd, w1[2], ga[6]); ga[7] = fmaf(hd, w1[3], ga[7]);
    }
    {
        unsigned short ob[8];
#pragma unroll
        for (int j = 0; j < 8; ++j) {
            float gg = 1.f / (1.f + __expf(-ga[j]));
            ob[j] = __builtin_bit_cast(unsigned short, __float2bfloat16(gg * tv[j]));
        }
        ushort4* go = (ushort4*)(gout + ((size_t)row << 6) + c0);
        ushort4 o0 = {ob[0], ob[1], ob[2], ob[3]};
        ushort4 o1 = {ob[4], ob[5], ob[6], ob[7]};
        go[0] = o0; go[1] = o1;
    }
}

// ---------------------------------------------------------------------------
extern "C" void kernel_launch(void* const* d_in, const int* in_sizes, int n_in,
                              void* d_out, int out_size, void* d_ws, size_t ws_size,
                              hipStream_t stream)
{
    const float* x    = (const float*)d_in[0];
    const float* Wg0  = (const float*)d_in[1];
    const float* bg0  = (const float*)d_in[2];
    const float* Wg1  = (const float*)d_in[3];
    const float* bg1  = (const float*)d_in[4];
    const float* Wout = (const float*)d_in[5];
    const float* bout = (const float*)d_in[6];
    const float* WA   = (const float*)d_in[7];
    const float* bA   = (const float*)d_in[8];
    const float* WB   = (const float*)d_in[9];
    const float* bB   = (const float*)d_in[10];
    const float* WD   = (const float*)d_in[11];
    const float* bD   = (const float*)d_in[12];
    const float* WC   = (const float*)d_in[13];
    const float* bC   = (const float*)d_in[14];
    const int* nmap[4] = {(const int*)d_in[15], (const int*)d_in[16],
                          (const int*)d_in[17], (const int*)d_in[18]};
    const int* ndm[3]  = {(const int*)d_in[19], (const int*)d_in[20],
                          (const int*)d_in[21]};

    float* out = (float*)d_out;
    __hip_bfloat16* featbf0 = (__hip_bfloat16*)d_ws;
    __hip_bfloat16* featbf1 = featbf0 + (size_t)N0 * 64;
    __hip_bfloat16* convbf  = featbf1 + (size_t)N0 * 64;
    float* conv32 = (float*)(convbf + (size_t)N0 * 64);   // up to 8 chunks of N2*64 f32
    __hip_bfloat16* WAt = (__hip_bfloat16*)(conv32 + (size_t)N2 * 64 * 8);
    __hip_bfloat16* WBt = WAt + 27 * 4096;
    __hip_bfloat16* WCt = WBt + 27 * 4096;
    __hip_bfloat16* WDt = WCt + 27 * 4096;

    const int Ns[4] = {N0, N1, N2, N3};
    size_t off[7];
    off[0] = 0;
    off[1] = off[0] + (size_t)N0 * 32;
    off[2] = off[1] + (size_t)N0 * 32;
    off[3] = off[2] + (size_t)N1 * 32;
    off[4] = off[3] + (size_t)N1 * 32;
    off[5] = off[4] + (size_t)N2 * 32;
    off[6] = off[5] + (size_t)N2 * 32;

    hipLaunchKernelGGL(prep_w4, dim3((89 * 4096 + 255) / 256), dim3(256), 0, stream,
                       WA, WB, WC, WD, WAt, 89 * 4096);

    // big scales run direct; small scales tap-split into ch partial buffers
    auto chunks = [&](int Nout, int K) -> int {
        if (Nout >= 16384) return 1;
        if (Nout == 4096) return (K == 27) ? 4 : 2;
        return (K == 27) ? 7 : 4;   // N3
    };
    // returns ch if result is f32 chunk partials in conv32, else 0 (bf16 in dst)
    auto conv = [&](const __hip_bfloat16* fin, const int* nm,
                    const __hip_bfloat16* Wt, int Nout, int K,
                    const float* bias2, void* dst, int mode) -> int {
        int ch = chunks(Nout, K);
        if (ch > 1) {
            hipLaunchKernelGGL(spconv_mfma, dim3(Nout / 64, ch), dim3(256), 0, stream,
                               fin, nm, Wt, (void*)conv32, (const float*)nullptr,
                               Nout, K, 1);
            return ch;
        }
        hipLaunchKernelGGL(spconv_mfma, dim3(Nout / 64, 1), dim3(256), 0, stream,
                           fin, nm, Wt, dst, bias2, Nout, K, mode);
        return 0;
    };

    // init: hx0 -> out0 ; featbf0 = bf16(sigmoid(hx0@Wg0+bg0) * x)
    hipLaunchKernelGGL(epi_full, dim3(N0 / 32), dim3(256), 0, stream,
                       (const void*)x, 2, 1, (const float*)nullptr, Wout, bout, Wg0, bg0,
                       out + off[0], featbf0, N0);

    for (int s = 0; s < 3; ++s) {
        int N = Ns[s], Nn = Ns[s + 1];

        // conv A (bias+relu) -> featbf1
        int mA = conv(featbf0, nmap[s], WAt, N, 27, bA, featbf1, 2);
        if (mA)
            hipLaunchKernelGGL(reduce_relu_bf, dim3((N * 16 + 255) / 256), dim3(256), 0, stream,
                               conv32, bA, featbf1, N * 16, mA);
        // conv B (raw) -> convbf or conv32 chunks ; epilogue fuses reduce+bias+relu+hx+gate
        int mB = conv(featbf1, nmap[s], WBt, N, 27, nullptr, convbf, 0);
        hipLaunchKernelGGL(epi_full, dim3(N / 32), dim3(256), 0, stream,
                           mB ? (const void*)conv32 : (const void*)convbf, mB ? 3 : 0, mB, bB,
                           Wout, bout, Wg1, bg1, out + off[s * 2 + 1], featbf0, N);

        // conv D (downsample, bias+relu) -> featbf1
        int mD = conv(featbf0, ndm[s], WDt, Nn, 8, bD, featbf1, 2);
        if (mD)
            hipLaunchKernelGGL(reduce_relu_bf, dim3((Nn * 16 + 255) / 256), dim3(256), 0, stream,
                               conv32, bD, featbf1, Nn * 16, mD);
        // conv C (raw) -> convbf or conv32 chunks ; epilogue
        int mC = conv(featbf1, nmap[s + 1], WCt, Nn, 27, nullptr, convbf, 0);
        hipLaunchKernelGGL(epi_full, dim3(Nn / 32), dim3(256), 0, stream,
                           mC ? (const void*)conv32 : (const void*)convbf, mC ? 3 : 0, mC, bC,
                           Wout, bout, Wg0, bg0, out + off[s * 2 + 2], featbf0, Nn);
    }
}